// Round 1
// baseline (5451.401 us; speedup 1.0000x reference)
//
#include <hip/hip_runtime.h>
#include <hip/hip_bf16.h>

// ---------------------------------------------------------------------------
// LSTM_37847251812594: 2-layer LSTM (B=256, T=64, n_x=512, n_h=1024) + FC+softmax
// Round 1: correctness-first bf16 MFMA baseline.
//   - weights pre-transposed to Wt[n][k] bf16 so A and B fragments are both
//     contiguous 16B loads (no LDS staging needed)
//   - one fused kernel per (t, layer): 4-gate GEMM + LSTM cell epilogue
//   - fp32 accumulate, fp32 cell state, fp32 pointwise math
//   - h double-buffered (kernel reads h[t&1], writes h[(t+1)&1]) -> no RAW race
// ---------------------------------------------------------------------------

typedef short  bf16x8 __attribute__((ext_vector_type(8)));
typedef float  f32x4  __attribute__((ext_vector_type(4)));

#define NHID 1024
#define NBATCH 256

__device__ __forceinline__ unsigned short f2b(float f) {
    unsigned int u = __builtin_bit_cast(unsigned int, f);
    unsigned int r = (u + 0x7FFFu + ((u >> 16) & 1u)) >> 16;
    return (unsigned short)r;
}
__device__ __forceinline__ float sigmoidf_(float x) {
    return 1.0f / (1.0f + __expf(-x));
}
__device__ __forceinline__ float tanhf_(float x) {
    // stable both directions: exp(2x)->inf => 1 ; exp(2x)->0 => -1
    return 1.0f - 2.0f / (__expf(2.0f * x) + 1.0f);
}

// Transpose+convert one layer's 4 gate matrices: W[k][n] fp32 -> Wt[g][n][k] bf16
__global__ void transpose_w_kernel(const float* __restrict__ w0, const float* __restrict__ w1,
                                   const float* __restrict__ w2, const float* __restrict__ w3,
                                   unsigned short* __restrict__ dst, int nv) {
    const int gate = blockIdx.y;
    const float* src = (gate == 0) ? w0 : (gate == 1) ? w1 : (gate == 2) ? w2 : w3;
    unsigned short* out = dst + (size_t)gate * NHID * nv;
    int idx = blockIdx.x * 256 + threadIdx.x;
    int total = NHID * nv;
    if (idx < total) {
        int n = idx / nv;
        int k = idx - n * nv;
        out[idx] = f2b(src[(size_t)k * NHID + n]);
    }
}

// fp32 -> bf16 elementwise (x), 4-wide
__global__ void cvt_x_kernel(const float* __restrict__ x, unsigned short* __restrict__ xb, int total4) {
    int idx = blockIdx.x * 256 + threadIdx.x;
    if (idx < total4) {
        float4 v = reinterpret_cast<const float4*>(x)[idx];
        ushort4 o;
        o.x = f2b(v.x); o.y = f2b(v.y); o.z = f2b(v.z); o.w = f2b(v.w);
        reinterpret_cast<ushort4*>(xb)[idx] = o;
    }
}

// Fused 4-gate GEMM + LSTM cell update for one (timestep, layer).
// D[n][m] = sum_k Wt[g][n][k] * x_in[m][k],  x_in = [h_prev | inp]
// Wave tile: 64 m (4 mf) x 16 n x 4 gates.  Grid: (256/64, 1024/16) = (4,64).
template<int NV>
__global__ __launch_bounds__(64)
void lstm_step_kernel(const unsigned short* __restrict__ wt,       // [4][1024][NV] bf16
                      const unsigned short* __restrict__ hprev,    // [256][1024] bf16
                      const unsigned short* __restrict__ inp,      // row m at inp + m*inp_stride
                      const int inp_stride,
                      const float* __restrict__ bF, const float* __restrict__ bI,
                      const float* __restrict__ bC, const float* __restrict__ bO,
                      float* __restrict__ c_state,                 // [256][1024] fp32 (rd+wr)
                      float* __restrict__ h_f32,                   // [256][1024] fp32 (wr)
                      unsigned short* __restrict__ h_b16) {        // [256][1024] bf16 (wr)
    const int lane = threadIdx.x;          // 0..63
    const int m0 = blockIdx.x * 64;
    const int n0 = blockIdx.y * 16;
    const int r  = lane & 15;
    const int kg = lane >> 4;              // 0..3
    const int kofs = kg * 8;

    // acc[g][mf] : 16x16 fragment, D row = n (bias axis), D col = m
    f32x4 acc[4][4];
    {
        const float* bias[4] = {bF, bI, bC, bO};
        #pragma unroll
        for (int g = 0; g < 4; ++g) {
            f32x4 bv;
            const float4 b4 = *reinterpret_cast<const float4*>(bias[g] + n0 + kg * 4);
            bv[0] = b4.x; bv[1] = b4.y; bv[2] = b4.z; bv[3] = b4.w;
            #pragma unroll
            for (int mf = 0; mf < 4; ++mf) acc[g][mf] = bv;
        }
    }

    // A (weights) pointers: row n = n0 + r, k starts at kofs
    const unsigned short* pA[4];
    #pragma unroll
    for (int g = 0; g < 4; ++g)
        pA[g] = wt + ((size_t)g * NHID + (n0 + r)) * NV + kofs;

    // B (x_in^T) pointers: col m = m0 + mf*16 + r
    const unsigned short* pBh[4];
    const unsigned short* pBx[4];
    #pragma unroll
    for (int mf = 0; mf < 4; ++mf) {
        int m = m0 + mf * 16 + r;
        pBh[mf] = hprev + (size_t)m * NHID + kofs;
        pBx[mf] = inp + (size_t)m * inp_stride + kofs;
    }

    // K over h_prev region: k in [0, 1024), 32 steps of K=32
    #pragma unroll 2
    for (int s = 0; s < 32; ++s) {
        bf16x8 b[4];
        #pragma unroll
        for (int mf = 0; mf < 4; ++mf)
            b[mf] = *reinterpret_cast<const bf16x8*>(pBh[mf] + s * 32);
        #pragma unroll
        for (int g = 0; g < 4; ++g) {
            bf16x8 a = *reinterpret_cast<const bf16x8*>(pA[g] + s * 32);
            #pragma unroll
            for (int mf = 0; mf < 4; ++mf)
                acc[g][mf] = __builtin_amdgcn_mfma_f32_16x16x32_bf16(a, b[mf], acc[g][mf], 0, 0, 0);
        }
    }

    // K over inp region: k in [1024, NV)
    constexpr int KX = (NV - 1024) / 32;
    #pragma unroll 2
    for (int s = 0; s < KX; ++s) {
        bf16x8 b[4];
        #pragma unroll
        for (int mf = 0; mf < 4; ++mf)
            b[mf] = *reinterpret_cast<const bf16x8*>(pBx[mf] + s * 32);
        #pragma unroll
        for (int g = 0; g < 4; ++g) {
            bf16x8 a = *reinterpret_cast<const bf16x8*>(pA[g] + 1024 + s * 32);
            #pragma unroll
            for (int mf = 0; mf < 4; ++mf)
                acc[g][mf] = __builtin_amdgcn_mfma_f32_16x16x32_bf16(a, b[mf], acc[g][mf], 0, 0, 0);
        }
    }

    // Epilogue: LSTM cell update.  C/D layout: col = lane&15 (m), row = (lane>>4)*4+reg (n).
    const int nb = n0 + kg * 4;
    #pragma unroll
    for (int mf = 0; mf < 4; ++mf) {
        const int m = m0 + mf * 16 + r;
        const size_t base = (size_t)m * NHID + nb;
        float4 cp = *reinterpret_cast<const float4*>(c_state + base);
        float4 cn, hn;
        ushort4 hb;
        float fv, iv, cv, ov, cc, hh;
        #define CELL(idx, comp)                                   \
            fv = sigmoidf_(acc[0][mf][idx]);                      \
            iv = sigmoidf_(acc[1][mf][idx]);                      \
            cv = tanhf_(acc[2][mf][idx]);                         \
            ov = sigmoidf_(acc[3][mf][idx]);                      \
            cc = fv * cp.comp + iv * cv;                          \
            hh = ov * tanhf_(cc);                                 \
            cn.comp = cc; hn.comp = hh;
        CELL(0, x) CELL(1, y) CELL(2, z) CELL(3, w)
        #undef CELL
        hb.x = f2b(hn.x); hb.y = f2b(hn.y); hb.z = f2b(hn.z); hb.w = f2b(hn.w);
        *reinterpret_cast<float4*>(c_state + base) = cn;
        *reinterpret_cast<float4*>(h_f32 + base)  = hn;
        *reinterpret_cast<ushort4*>(h_b16 + base) = hb;
    }
}

// logits = h1 @ W + b   (fp32 exact; W is [1024][1000] row-major)
__global__ void classifier_kernel(const float* __restrict__ h, const float* __restrict__ W,
                                  const float* __restrict__ b, float* __restrict__ logits) {
    const int n = blockIdx.x * 256 + threadIdx.x;
    const int m = blockIdx.y;
    if (n >= 1000) return;
    const float* hr = h + (size_t)m * NHID;
    float acc = b[n];
    #pragma unroll 4
    for (int k = 0; k < NHID; ++k)
        acc = fmaf(hr[k], W[(size_t)k * 1000 + n], acc);
    logits[(size_t)m * 1000 + n] = acc;
}

__global__ void softmax_kernel(const float* __restrict__ logits, float* __restrict__ pred) {
    __shared__ float red[256];
    const int m = blockIdx.x;
    const int t = threadIdx.x;
    const float* lr = logits + (size_t)m * 1000;
    float mx = -3.4e38f;
    for (int i = t; i < 1000; i += 256) mx = fmaxf(mx, lr[i]);
    red[t] = mx; __syncthreads();
    for (int off = 128; off > 0; off >>= 1) {
        if (t < off) red[t] = fmaxf(red[t], red[t + off]);
        __syncthreads();
    }
    mx = red[0];
    __syncthreads();
    float sm = 0.0f;
    for (int i = t; i < 1000; i += 256) sm += __expf(lr[i] - mx);
    red[t] = sm; __syncthreads();
    for (int off = 128; off > 0; off >>= 1) {
        if (t < off) red[t] += red[t + off];
        __syncthreads();
    }
    const float inv = 1.0f / red[0];
    for (int i = t; i < 1000; i += 256)
        pred[(size_t)m * 1000 + i] = __expf(lr[i] - mx) * inv;
}

extern "C" void kernel_launch(void* const* d_in, const int* in_sizes, int n_in,
                              void* d_out, int out_size, void* d_ws, size_t ws_size,
                              hipStream_t stream) {
    (void)in_sizes; (void)n_in; (void)out_size; (void)ws_size;
    const float* x = (const float*)d_in[0];
    const float* W0[4] = {(const float*)d_in[1], (const float*)d_in[2], (const float*)d_in[3], (const float*)d_in[4]};
    const float* B0[4] = {(const float*)d_in[5], (const float*)d_in[6], (const float*)d_in[7], (const float*)d_in[8]};
    const float* W1[4] = {(const float*)d_in[9], (const float*)d_in[10], (const float*)d_in[11], (const float*)d_in[12]};
    const float* B1[4] = {(const float*)d_in[13], (const float*)d_in[14], (const float*)d_in[15], (const float*)d_in[16]};
    const float* Wc = (const float*)d_in[17];
    const float* bc = (const float*)d_in[18];
    float* out = (float*)d_out;

    // workspace carve-up (~53 MB total)
    char* ws = (char*)d_ws;
    size_t off = 0;
    auto alloc = [&](size_t bytes) -> char* {
        char* p = ws + off;
        off += (bytes + 255) & ~(size_t)255;
        return p;
    };
    unsigned short* wt0 = (unsigned short*)alloc((size_t)4 * NHID * 1536 * 2);
    unsigned short* wt1 = (unsigned short*)alloc((size_t)4 * NHID * 2048 * 2);
    unsigned short* xb  = (unsigned short*)alloc((size_t)NBATCH * 64 * 512 * 2);
    char* states = ws + off;
    unsigned short* h0b = (unsigned short*)alloc((size_t)2 * NBATCH * NHID * 2);  // double-buffered
    unsigned short* h1b = (unsigned short*)alloc((size_t)2 * NBATCH * NHID * 2);
    float* c0 = (float*)alloc((size_t)NBATCH * NHID * 4);
    float* c1 = (float*)alloc((size_t)NBATCH * NHID * 4);
    size_t state_bytes = (size_t)((char*)c1 + (size_t)NBATCH * NHID * 4 - states);
    float* h0f = (float*)alloc((size_t)NBATCH * NHID * 4);
    float* h1f = (float*)alloc((size_t)NBATCH * NHID * 4);

    hipMemsetAsync(states, 0, state_bytes, stream);

    transpose_w_kernel<<<dim3((NHID * 1536 + 255) / 256, 4), 256, 0, stream>>>(
        W0[0], W0[1], W0[2], W0[3], wt0, 1536);
    transpose_w_kernel<<<dim3((NHID * 2048 + 255) / 256, 4), 256, 0, stream>>>(
        W1[0], W1[1], W1[2], W1[3], wt1, 2048);
    cvt_x_kernel<<<(NBATCH * 64 * 512 / 4 + 255) / 256, 256, 0, stream>>>(
        x, xb, NBATCH * 64 * 512 / 4);

    const int HSZ = NBATCH * NHID;
    for (int t = 0; t < 64; ++t) {
        const int cur = t & 1, nxt = cur ^ 1;
        lstm_step_kernel<1536><<<dim3(4, 64), 64, 0, stream>>>(
            wt0, h0b + (size_t)cur * HSZ, xb + (size_t)t * 512, 64 * 512,
            B0[0], B0[1], B0[2], B0[3], c0, h0f, h0b + (size_t)nxt * HSZ);
        lstm_step_kernel<2048><<<dim3(4, 64), 64, 0, stream>>>(
            wt1, h1b + (size_t)cur * HSZ, h0b + (size_t)nxt * HSZ, NHID,
            B1[0], B1[1], B1[2], B1[3], c1, h1f, h1b + (size_t)nxt * HSZ);
    }

    classifier_kernel<<<dim3(4, NBATCH), 256, 0, stream>>>(h1f, Wc, bc, out);
    softmax_kernel<<<NBATCH, 256, 0, stream>>>(out, out + (size_t)NBATCH * 1000);
}

// Round 2
// 4508.811 us; speedup vs baseline: 1.2091x; 1.2091x over previous
//
#include <hip/hip_runtime.h>
#include <hip/hip_bf16.h>

// ---------------------------------------------------------------------------
// LSTM_37847251812594: 2-layer LSTM (B=256, T=64, n_x=512, n_h=1024) + FC+softmax
// Round 2: occupancy fix.
//   - step kernel: 512 threads = 8 waves = 4 gates x 2 K-halves (2 waves/SIMD,
//     was 0.25); LDS exchange for cross-gate/k-half reduce + fused cell epilogue
//   - classifier: 8-way k-unroll, 8 independent accumulators
//   - weight transpose: LDS-tiled (coalesced both sides)
// ---------------------------------------------------------------------------

typedef short  bf16x8 __attribute__((ext_vector_type(8)));
typedef float  f32x4  __attribute__((ext_vector_type(4)));

#define NHID 1024
#define NBATCH 256

__device__ __forceinline__ unsigned short f2b(float f) {
    unsigned int u = __builtin_bit_cast(unsigned int, f);
    unsigned int r = (u + 0x7FFFu + ((u >> 16) & 1u)) >> 16;
    return (unsigned short)r;
}
__device__ __forceinline__ float sigmoidf_(float x) {
    return 1.0f / (1.0f + __expf(-x));
}
__device__ __forceinline__ float tanhf_(float x) {
    return 1.0f - 2.0f / (__expf(2.0f * x) + 1.0f);
}

// Transpose+convert: W[k][n] fp32 -> Wt[g][n][k] bf16, LDS-tiled 64x64.
__global__ __launch_bounds__(256)
void transpose_w_kernel(const float* __restrict__ w0, const float* __restrict__ w1,
                        const float* __restrict__ w2, const float* __restrict__ w3,
                        unsigned short* __restrict__ dst, int nv) {
    __shared__ unsigned short t[64][65];
    const int gate = blockIdx.z;
    const float* src = (gate == 0) ? w0 : (gate == 1) ? w1 : (gate == 2) ? w2 : w3;
    const int kt = blockIdx.x * 64;   // k-tile base
    const int nt = blockIdx.y * 64;   // n-tile base
    const int tid = threadIdx.x;
    const int rr = tid >> 6;          // 0..3
    const int cc = tid & 63;
    #pragma unroll
    for (int p = 0; p < 16; ++p) {
        const int row = p * 4 + rr;   // k-local
        t[cc][row] = f2b(src[(size_t)(kt + row) * NHID + nt + cc]);  // coalesced read
    }
    __syncthreads();
    #pragma unroll
    for (int p = 0; p < 16; ++p) {
        const int row = p * 4 + rr;   // n-local
        dst[((size_t)gate * NHID + nt + row) * nv + kt + cc] = t[row][cc];  // coalesced write
    }
}

// fp32 -> bf16 elementwise, 4-wide
__global__ void cvt_x_kernel(const float* __restrict__ x, unsigned short* __restrict__ xb, int total4) {
    int idx = blockIdx.x * 256 + threadIdx.x;
    if (idx < total4) {
        float4 v = reinterpret_cast<const float4*>(x)[idx];
        ushort4 o;
        o.x = f2b(v.x); o.y = f2b(v.y); o.z = f2b(v.z); o.w = f2b(v.w);
        reinterpret_cast<ushort4*>(xb)[idx] = o;
    }
}

// Fused 4-gate GEMM + LSTM cell update for one (timestep, layer).
// Block: 512 thr = 8 waves = (gate g = w&3) x (k-half kh = w>>2).
// Wave tile: 16n x 64m, K-range [kh*NV/2, (kh+1)*NV/2).
// x_in = [h_prev (k<1024) | inp (k>=1024)].
// Partials exchanged via LDS; 256-thread fused cell epilogue.
template<int NV>
__global__ __launch_bounds__(512)
void lstm_step_kernel(const unsigned short* __restrict__ wt,       // [4][1024][NV] bf16
                      const unsigned short* __restrict__ hprev,    // [256][1024] bf16
                      const unsigned short* __restrict__ inp,      // row m at inp + m*inp_stride
                      const int inp_stride,
                      const float* __restrict__ bF, const float* __restrict__ bI,
                      const float* __restrict__ bC, const float* __restrict__ bO,
                      float* __restrict__ c_state,                 // [256][1024] fp32 (rd+wr)
                      float* __restrict__ h_f32,                   // optional [256][1024] fp32 (wr)
                      unsigned short* __restrict__ h_b16) {        // [256][1024] bf16 (wr)
    __shared__ float lds[8 * 1024];

    const int tid  = threadIdx.x;
    const int lane = tid & 63;
    const int w    = tid >> 6;          // 0..7
    const int g    = w & 3;             // gate
    const int kh   = w >> 2;            // k-half
    const int m0 = blockIdx.x * 64;
    const int n0 = blockIdx.y * 16;
    const int r  = lane & 15;
    const int kg = lane >> 4;           // 0..3
    const int kofs = kg * 8;

    constexpr int KH = NV / 2;
    const int kstart = kh * KH;
    int rem_h = 1024 - kstart;
    if (rem_h < 0) rem_h = 0;
    if (rem_h > KH) rem_h = KH;
    const int steps_h = rem_h >> 5;            // K=32 steps over h_prev region
    const int steps_x = (KH >> 5) - steps_h;   // K=32 steps over inp region
    const int kx0 = kstart + steps_h * 32 - 1024;  // inp-local k base for loop 2

    // acc[mf]: 16x16 fragment, D row = n, D col = m.  Bias on kh==0 only.
    f32x4 acc[4];
    if (kh == 0) {
        const float* bias = (g == 0) ? bF : (g == 1) ? bI : (g == 2) ? bC : bO;
        const float4 b4 = *reinterpret_cast<const float4*>(bias + n0 + kg * 4);
        f32x4 bv; bv[0] = b4.x; bv[1] = b4.y; bv[2] = b4.z; bv[3] = b4.w;
        #pragma unroll
        for (int mf = 0; mf < 4; ++mf) acc[mf] = bv;
    } else {
        #pragma unroll
        for (int mf = 0; mf < 4; ++mf) acc[mf] = (f32x4)0.0f;
    }

    // A (weights): row n = n0 + r
    const unsigned short* pA = wt + ((size_t)g * NHID + (n0 + r)) * NV + kstart + kofs;
    // B (x_in^T): col m = m0 + mf*16 + r
    const unsigned short* pBh[4];
    const unsigned short* pBx[4];
    #pragma unroll
    for (int mf = 0; mf < 4; ++mf) {
        const int m = m0 + mf * 16 + r;
        pBh[mf] = hprev + (size_t)m * NHID + kstart + kofs;
        pBx[mf] = inp + (size_t)m * inp_stride + kx0 + kofs;
    }

    #pragma unroll 4
    for (int s = 0; s < steps_h; ++s) {
        const bf16x8 a = *reinterpret_cast<const bf16x8*>(pA + s * 32);
        #pragma unroll
        for (int mf = 0; mf < 4; ++mf) {
            const bf16x8 b = *reinterpret_cast<const bf16x8*>(pBh[mf] + s * 32);
            acc[mf] = __builtin_amdgcn_mfma_f32_16x16x32_bf16(a, b, acc[mf], 0, 0, 0);
        }
    }
    const unsigned short* pA2 = pA + steps_h * 32;
    #pragma unroll 4
    for (int s = 0; s < steps_x; ++s) {
        const bf16x8 a = *reinterpret_cast<const bf16x8*>(pA2 + s * 32);
        #pragma unroll
        for (int mf = 0; mf < 4; ++mf) {
            const bf16x8 b = *reinterpret_cast<const bf16x8*>(pBx[mf] + s * 32);
            acc[mf] = __builtin_amdgcn_mfma_f32_16x16x32_bf16(a, b, acc[mf], 0, 0, 0);
        }
    }

    // Exchange partials: lds[w][nl][ml], nl = kg*4+j (0..15), ml = mf*16+r (0..63)
    {
        float* ldsw = lds + w * 1024;
        #pragma unroll
        for (int mf = 0; mf < 4; ++mf)
            #pragma unroll
            for (int j = 0; j < 4; ++j)
                ldsw[(kg * 4 + j) * 64 + mf * 16 + r] = acc[mf][j];
    }
    __syncthreads();

    // Fused cell epilogue on 256 threads: thread -> (ml = tid&63, ng = tid>>6)
    if (tid < 256) {
        const int ml = tid & 63;
        const int ng = tid >> 6;
        const int m = m0 + ml;
        const size_t base = (size_t)m * NHID + n0 + ng * 4;
        const float4 cp = *reinterpret_cast<const float4*>(c_state + base);
        float cpj[4] = {cp.x, cp.y, cp.z, cp.w};
        float4 cn, hn;
        ushort4 hb;
        float cnj[4], hnj[4];
        #pragma unroll
        for (int j = 0; j < 4; ++j) {
            const int o = (ng * 4 + j) * 64 + ml;
            const float fs = lds[o]        + lds[4096 + o];
            const float is = lds[1024 + o] + lds[5120 + o];
            const float cs = lds[2048 + o] + lds[6144 + o];
            const float os = lds[3072 + o] + lds[7168 + o];
            const float fv = sigmoidf_(fs);
            const float iv = sigmoidf_(is);
            const float cv = tanhf_(cs);
            const float ov = sigmoidf_(os);
            const float cc = fv * cpj[j] + iv * cv;
            const float hh = ov * tanhf_(cc);
            cnj[j] = cc; hnj[j] = hh;
        }
        cn.x = cnj[0]; cn.y = cnj[1]; cn.z = cnj[2]; cn.w = cnj[3];
        hn.x = hnj[0]; hn.y = hnj[1]; hn.z = hnj[2]; hn.w = hnj[3];
        hb.x = f2b(hnj[0]); hb.y = f2b(hnj[1]); hb.z = f2b(hnj[2]); hb.w = f2b(hnj[3]);
        *reinterpret_cast<float4*>(c_state + base) = cn;
        *reinterpret_cast<ushort4*>(h_b16 + base) = hb;
        if (h_f32) *reinterpret_cast<float4*>(h_f32 + base) = hn;
    }
}

// logits = h1 @ W + b  (fp32; 8 independent k-accumulators for MLP)
__global__ __launch_bounds__(256)
void classifier_kernel(const float* __restrict__ h, const float* __restrict__ W,
                       const float* __restrict__ b, float* __restrict__ logits) {
    const int n = blockIdx.x * 256 + threadIdx.x;
    const int m = blockIdx.y;
    if (n >= 1000) return;
    const float* hr = h + (size_t)m * NHID;
    float acc[8];
    #pragma unroll
    for (int u = 0; u < 8; ++u) acc[u] = 0.0f;
    for (int k = 0; k < NHID; k += 8) {
        #pragma unroll
        for (int u = 0; u < 8; ++u)
            acc[u] = fmaf(hr[k + u], W[(size_t)(k + u) * 1000 + n], acc[u]);
    }
    float s = b[n];
    #pragma unroll
    for (int u = 0; u < 8; ++u) s += acc[u];
    logits[(size_t)m * 1000 + n] = s;
}

__global__ void softmax_kernel(const float* __restrict__ logits, float* __restrict__ pred) {
    __shared__ float red[256];
    const int m = blockIdx.x;
    const int t = threadIdx.x;
    const float* lr = logits + (size_t)m * 1000;
    float mx = -3.4e38f;
    for (int i = t; i < 1000; i += 256) mx = fmaxf(mx, lr[i]);
    red[t] = mx; __syncthreads();
    for (int off = 128; off > 0; off >>= 1) {
        if (t < off) red[t] = fmaxf(red[t], red[t + off]);
        __syncthreads();
    }
    mx = red[0];
    __syncthreads();
    float sm = 0.0f;
    for (int i = t; i < 1000; i += 256) sm += __expf(lr[i] - mx);
    red[t] = sm; __syncthreads();
    for (int off = 128; off > 0; off >>= 1) {
        if (t < off) red[t] += red[t + off];
        __syncthreads();
    }
    const float inv = 1.0f / red[0];
    for (int i = t; i < 1000; i += 256)
        pred[(size_t)m * 1000 + i] = __expf(lr[i] - mx) * inv;
}

extern "C" void kernel_launch(void* const* d_in, const int* in_sizes, int n_in,
                              void* d_out, int out_size, void* d_ws, size_t ws_size,
                              hipStream_t stream) {
    (void)in_sizes; (void)n_in; (void)out_size; (void)ws_size;
    const float* x = (const float*)d_in[0];
    const float* W0[4] = {(const float*)d_in[1], (const float*)d_in[2], (const float*)d_in[3], (const float*)d_in[4]};
    const float* B0[4] = {(const float*)d_in[5], (const float*)d_in[6], (const float*)d_in[7], (const float*)d_in[8]};
    const float* W1[4] = {(const float*)d_in[9], (const float*)d_in[10], (const float*)d_in[11], (const float*)d_in[12]};
    const float* B1[4] = {(const float*)d_in[13], (const float*)d_in[14], (const float*)d_in[15], (const float*)d_in[16]};
    const float* Wc = (const float*)d_in[17];
    const float* bc = (const float*)d_in[18];
    float* out = (float*)d_out;

    char* ws = (char*)d_ws;
    size_t off = 0;
    auto alloc = [&](size_t bytes) -> char* {
        char* p = ws + off;
        off += (bytes + 255) & ~(size_t)255;
        return p;
    };
    unsigned short* wt0 = (unsigned short*)alloc((size_t)4 * NHID * 1536 * 2);
    unsigned short* wt1 = (unsigned short*)alloc((size_t)4 * NHID * 2048 * 2);
    unsigned short* xb  = (unsigned short*)alloc((size_t)NBATCH * 64 * 512 * 2);
    char* states = ws + off;
    unsigned short* h0b = (unsigned short*)alloc((size_t)2 * NBATCH * NHID * 2);  // double-buffered
    unsigned short* h1b = (unsigned short*)alloc((size_t)2 * NBATCH * NHID * 2);
    float* c0 = (float*)alloc((size_t)NBATCH * NHID * 4);
    float* c1 = (float*)alloc((size_t)NBATCH * NHID * 4);
    size_t state_bytes = (size_t)((char*)c1 + (size_t)NBATCH * NHID * 4 - states);
    float* h1f = (float*)alloc((size_t)NBATCH * NHID * 4);

    hipMemsetAsync(states, 0, state_bytes, stream);

    transpose_w_kernel<<<dim3(1536 / 64, 16, 4), 256, 0, stream>>>(
        W0[0], W0[1], W0[2], W0[3], wt0, 1536);
    transpose_w_kernel<<<dim3(2048 / 64, 16, 4), 256, 0, stream>>>(
        W1[0], W1[1], W1[2], W1[3], wt1, 2048);
    cvt_x_kernel<<<(NBATCH * 64 * 512 / 4 + 255) / 256, 256, 0, stream>>>(
        x, xb, NBATCH * 64 * 512 / 4);

    const int HSZ = NBATCH * NHID;
    for (int t = 0; t < 64; ++t) {
        const int cur = t & 1, nxt = cur ^ 1;
        lstm_step_kernel<1536><<<dim3(4, 64), 512, 0, stream>>>(
            wt0, h0b + (size_t)cur * HSZ, xb + (size_t)t * 512, 64 * 512,
            B0[0], B0[1], B0[2], B0[3], c0, nullptr, h0b + (size_t)nxt * HSZ);
        lstm_step_kernel<2048><<<dim3(4, 64), 512, 0, stream>>>(
            wt1, h1b + (size_t)cur * HSZ, h0b + (size_t)nxt * HSZ, NHID,
            B1[0], B1[1], B1[2], B1[3], c1, (t == 63) ? h1f : nullptr,
            h1b + (size_t)nxt * HSZ);
    }

    classifier_kernel<<<dim3(4, NBATCH), 256, 0, stream>>>(h1f, Wc, bc, out);
    softmax_kernel<<<NBATCH, 256, 0, stream>>>(out, out + (size_t)NBATCH * 1000);
}